// Round 2
// baseline (1843.922 us; speedup 1.0000x reference)
//
#include <hip/hip_runtime.h>
#include <cstdint>
#include <cstddef>

typedef __bf16 bf16_t;
typedef __bf16 bf16x8 __attribute__((ext_vector_type(8)));
typedef __bf16 bf16x4 __attribute__((ext_vector_type(4)));
typedef __bf16 bf16x2 __attribute__((ext_vector_type(2)));
typedef float f32x4 __attribute__((ext_vector_type(4)));

#define A_TOTAL 262144
#define NMAP    131072

// ---------------- prep: W1 slices f32->bf16  +  W2 -> extended [272][256] --
__global__ __launch_bounds__(256) void k_prep(
    const float* __restrict__ mW1, const float* __restrict__ sW1,
    bf16_t* __restrict__ w1b,
    const float* __restrict__ mW2, const float* __restrict__ sW2,
    bf16_t* __restrict__ wext) {
  int b = blockIdx.x, t = threadIdx.x;
  if (b < 1024) {
    int e = b * 256 + t;                       // 0..262143
    int slice = e >> 16, idx = e & 65535;
    int n = idx >> 8, k = idx & 255;
    float v;
    switch (slice) {
      case 0:  v = mW1[n * 512 + k]; break;
      case 1:  v = mW1[n * 512 + 256 + k]; break;
      case 2:  v = sW1[n * 512 + k]; break;
      default: v = sW1[n * 512 + 256 + k]; break;
    }
    w1b[e] = (bf16_t)v;
  } else {
    int e2 = b - 1024;                         // 0..543
    int tab = e2 >= 272 ? 1 : 0;
    int row = e2 - tab * 272;
    const float* W2 = tab ? sW2 : mW2;
    bf16_t v = (row < 256) ? (bf16_t)W2[row * 256 + t] : (bf16_t)0.f;
    wext[(size_t)tab * 272 * 256 + (size_t)row * 256 + t] = v;
  }
}

// ---------------- column partial sums of all_embeddings [131072][256] ------
__global__ __launch_bounds__(256) void k_mean(const float* __restrict__ A,
                                              float* __restrict__ part) {
  int t = threadIdx.x, b = blockIdx.x;        // 512 blocks x 256 rows
  const float* base = A + (size_t)b * 256 * 256 + t;
  float s = 0.f;
  for (int r = 0; r < 256; ++r) s += base[(size_t)r * 256];
  part[b * 256 + t] = s;
}

// ---------------- g -> query MLP -> q -> qk -> qw rows of Wext -------------
__global__ __launch_bounds__(256) void k_front(
    const float* __restrict__ meanPart,
    const float* __restrict__ qgW1, const float* __restrict__ qgb1,
    const float* __restrict__ qgW2, const float* __restrict__ qgb2,
    const float* __restrict__ Wq,  const float* __restrict__ bq,
    const float* __restrict__ Wk,
    const float* __restrict__ mW2, const float* __restrict__ sW2,
    bf16_t* __restrict__ wext) {
  __shared__ float g[256], h1[256], qry[256], qv[256];
  __shared__ float qks[4][256];
  int t = threadIdx.x;
  float s = 0.f;
  for (int b = 0; b < 512; ++b) s += meanPart[b * 256 + t];
  g[t] = s * (1.0f / 131072.0f);
  __syncthreads();
  {
    const f32x4* row = (const f32x4*)(qgW1 + (size_t)t * 256);
    float acc = 0.f;
    for (int k = 0; k < 64; ++k) {
      f32x4 w = row[k];
      acc += w[0] * g[4 * k] + w[1] * g[4 * k + 1] + w[2] * g[4 * k + 2] + w[3] * g[4 * k + 3];
    }
    h1[t] = fmaxf(acc + qgb1[t], 0.f);
  }
  __syncthreads();
  {
    const f32x4* row = (const f32x4*)(qgW2 + (size_t)t * 256);
    float acc = 0.f;
    for (int k = 0; k < 64; ++k) {
      f32x4 w = row[k];
      acc += w[0] * h1[4 * k] + w[1] * h1[4 * k + 1] + w[2] * h1[4 * k + 2] + w[3] * h1[4 * k + 3];
    }
    qry[t] = acc + qgb2[t];
  }
  __syncthreads();
  {
    const f32x4* row = (const f32x4*)(Wq + (size_t)t * 256);
    float acc = 0.f;
    for (int k = 0; k < 64; ++k) {
      f32x4 w = row[k];
      acc += w[0] * qry[4 * k] + w[1] * qry[4 * k + 1] + w[2] * qry[4 * k + 2] + w[3] * qry[4 * k + 3];
    }
    qv[t] = acc + bq[t];
  }
  __syncthreads();
  for (int h = 0; h < 4; ++h) {
    float acc = 0.f;
    for (int d = 0; d < 64; ++d) acc += qv[h * 64 + d] * Wk[(size_t)(h * 64 + d) * 256 + t];
    qks[h][t] = acc * 0.125f;
  }
  __syncthreads();
  for (int tab = 0; tab < 2; ++tab) {
    const float* W2 = tab ? sW2 : mW2;
    float acc0 = 0.f, acc1 = 0.f, acc2 = 0.f, acc3 = 0.f;
    for (int n = 0; n < 256; ++n) {
      float wv = W2[(size_t)n * 256 + t];
      acc0 += qks[0][n] * wv;
      acc1 += qks[1][n] * wv;
      acc2 += qks[2][n] * wv;
      acc3 += qks[3][n] * wv;
    }
    bf16_t* dst = wext + (size_t)tab * 272 * 256;
    dst[(256 + 0) * 256 + t] = (bf16_t)acc0;
    dst[(256 + 1) * 256 + t] = (bf16_t)acc1;
    dst[(256 + 2) * 256 + t] = (bf16_t)acc2;
    dst[(256 + 3) * 256 + t] = (bf16_t)acc3;
  }
}

// ---------------- GEMM (direct, merged 2 problem halves) -------------------
__global__ __launch_bounds__(512, 4) void gemm_direct3(
    const float* __restrict__ A0, int M0, const bf16_t* __restrict__ W0,
    const float* __restrict__ b0, bf16_t* __restrict__ C0, int split,
    const float* __restrict__ A1, int M1, const bf16_t* __restrict__ W1,
    const float* __restrict__ b1, bf16_t* __restrict__ C1) {
  __shared__ __align__(16) bf16_t Xo[128][264];   // 67584 B
  int blk = blockIdx.x;
  const float* A; int M; const bf16_t* W; const float* bias; bf16_t* C; int bid;
  if (blk < split) { A = A0; M = M0; W = W0; bias = b0; C = C0; bid = blk; }
  else             { A = A1; M = M1; W = W1; bias = b1; C = C1; bid = blk - split; }
  int t = threadIdx.x;
  int w = t >> 6, lane = t & 63;
  int lm = lane & 15, q = lane >> 4;
  int mloc0 = (w & 1) * 64;
  int m0 = bid * 128 + mloc0;
  int c0 = (w >> 1) * 64;
  int rows[4];
#pragma unroll
  for (int i = 0; i < 4; ++i) {
    int m = m0 + i * 16 + lm;
    rows[i] = m < M ? m : M - 1;
  }
  f32x4 acc[4][4] = {};
#pragma unroll
  for (int kt = 0; kt < 8; ++kt) {
    int k0 = kt * 32 + q * 8;
    bf16x8 b[4];
#pragma unroll
    for (int j = 0; j < 4; ++j)
      b[j] = *(const bf16x8*)(W + (size_t)(c0 + j * 16 + lm) * 256 + k0);
#pragma unroll
    for (int i = 0; i < 4; ++i) {
      const float* src = A + (size_t)rows[i] * 256 + k0;
      f32x4 lo = *(const f32x4*)src;
      f32x4 hi = *(const f32x4*)(src + 4);
      bf16x8 a;
#pragma unroll
      for (int x = 0; x < 4; ++x) { a[x] = (bf16_t)lo[x]; a[x + 4] = (bf16_t)hi[x]; }
#pragma unroll
      for (int j = 0; j < 4; ++j)
        acc[i][j] = __builtin_amdgcn_mfma_f32_16x16x32_bf16(a, b[j], acc[i][j], 0, 0, 0);
    }
  }
#pragma unroll
  for (int j = 0; j < 4; ++j) {
    int col = c0 + j * 16 + lm;
    float bb = bias ? bias[col] : 0.f;
#pragma unroll
    for (int i = 0; i < 4; ++i)
#pragma unroll
      for (int r = 0; r < 4; ++r)
        Xo[mloc0 + i * 16 + q * 4 + r][col] = (bf16_t)(acc[i][j][r] + bb);
  }
  __syncthreads();
  size_t tile0 = (size_t)bid * 128;
  const char* lds = (const char*)&Xo[0][0];
#pragma unroll
  for (int s = 0; s < 8; ++s) {
    int flat = s * 8192 + t * 16;
    int row = flat >> 9, colb = flat & 511;
    if (tile0 + (size_t)row < (size_t)M) {
      uint4 v = *(const uint4*)(lds + row * 528 + colb);
      *(uint4*)((char*)C + tile0 * 512 + (size_t)flat) = v;
    }
  }
}

// ---------------- GEMM (gather, direct per-lane) + fused scores ------------
// 256 thr = 4 waves (col split), tile 32 rows x 256 cols. No K-loop barriers:
// each lane gathers its A-fragment (relu(Pa+Pb)) straight from global.
// Last block reduces partMax -> Mh.
__global__ __launch_bounds__(256, 4) void gemm_gather4(
    const bf16_t* __restrict__ Pa0, const bf16_t* __restrict__ Pb0,
    const int* __restrict__ idxA0, const int* __restrict__ idxB0,
    const bf16_t* __restrict__ Wext0, const float* __restrict__ bias0,
    const bf16_t* __restrict__ Pa1, const bf16_t* __restrict__ Pb1,
    const int* __restrict__ idxA1, const int* __restrict__ idxB1,
    const bf16_t* __restrict__ Wext1, const float* __restrict__ bias1,
    bf16_t* __restrict__ C,
    float* __restrict__ scores, float* __restrict__ partMax,
    int* __restrict__ cnt, float* __restrict__ Mh) {
  __shared__ __align__(16) bf16_t Xo[32][264];   // 16.9 KB (also last-block scratch)
  __shared__ float sred[4];
  __shared__ int isLast;
  int blk = blockIdx.x;
  int half = blk >> 12, bid = blk & 4095;
  const bf16_t* Pa; const bf16_t* Pb; const int* idxA; const int* idxB;
  const bf16_t* Wext; const float* bias;
  if (half == 0) { Pa = Pa0; Pb = Pb0; idxA = idxA0; idxB = idxB0; Wext = Wext0; bias = bias0; }
  else           { Pa = Pa1; Pb = Pb1; idxA = idxA1; idxB = idxB1; Wext = Wext1; bias = bias1; }
  int scoreBase = half * NMAP;
  int pmBase = half * 4096;

  int t = threadIdx.x;
  int w = t >> 6, lane = t & 63;
  int lm = lane & 15, q = lane >> 4;
  int cw = w * 64;
  int row0 = bid * 32;

  // per-lane gather bases (row i*16+lm, col chunk q*8)
  const bf16_t* pa[2]; const bf16_t* pb[2];
#pragma unroll
  for (int i = 0; i < 2; ++i) {
    int r = row0 + i * 16 + lm;
    pa[i] = Pa + (size_t)idxA[r] * 256 + q * 8;
    pb[i] = Pb + (size_t)idxB[r] * 256 + q * 8;
  }

  f32x4 acc[2][4] = {};
  f32x4 accs[2] = {};
  bool doScore = (w == 0);
#pragma unroll
  for (int kt = 0; kt < 8; ++kt) {
    int kc = kt * 32;
    int kq = kc + q * 8;
    bf16x8 a[2];
#pragma unroll
    for (int i = 0; i < 2; ++i) {
      bf16x8 va = *(const bf16x8*)(pa[i] + kc);
      bf16x8 vb = *(const bf16x8*)(pb[i] + kc);
      bf16x8 x;
#pragma unroll
      for (int e = 0; e < 8; ++e)
        x[e] = (bf16_t)fmaxf((float)va[e] + (float)vb[e], 0.f);
      a[i] = x;
    }
#pragma unroll
    for (int j = 0; j < 4; ++j) {
      bf16x8 b = *(const bf16x8*)(Wext + (size_t)(cw + j * 16 + lm) * 256 + kq);
#pragma unroll
      for (int i = 0; i < 2; ++i)
        acc[i][j] = __builtin_amdgcn_mfma_f32_16x16x32_bf16(a[i], b, acc[i][j], 0, 0, 0);
    }
    if (doScore) {
      bf16x8 bs = *(const bf16x8*)(Wext + (size_t)(256 + lm) * 256 + kq);
#pragma unroll
      for (int i = 0; i < 2; ++i)
        accs[i] = __builtin_amdgcn_mfma_f32_16x16x32_bf16(a[i], bs, accs[i], 0, 0, 0);
    }
  }
  // stage bias-added bf16 keys in LDS
#pragma unroll
  for (int j = 0; j < 4; ++j) {
    int col = cw + j * 16 + lm;
    float bb = bias[col];
#pragma unroll
    for (int i = 0; i < 2; ++i)
#pragma unroll
      for (int rr = 0; rr < 4; ++rr)
        Xo[i * 16 + q * 4 + rr][col] = (bf16_t)(acc[i][j][rr] + bb);
  }
  // scores epilogue (wave 0; lanes lm<4 hold head lm)
  float hmax = -3.4e38f;
  if (doScore) {
    if (lm < 4) {
#pragma unroll
      for (int i = 0; i < 2; ++i)
#pragma unroll
        for (int rr = 0; rr < 4; ++rr) {
          int m = i * 16 + q * 4 + rr;
          float v = accs[i][rr];
          scores[(size_t)lm * A_TOTAL + scoreBase + row0 + m] = v;
          hmax = fmaxf(hmax, v);
        }
    }
    float m1 = fmaxf(hmax, __shfl_xor(hmax, 16));
    float m2 = fmaxf(m1, __shfl_xor(m1, 32));
    if (lane < 4) sred[lane] = m2;
  }
  __syncthreads();
  // flat coalesced write: 32 rows x 512 B
  size_t gRow0 = (size_t)(half * NMAP + row0);
  const char* lds = (const char*)&Xo[0][0];
#pragma unroll
  for (int s = 0; s < 4; ++s) {
    int flat = s * 4096 + t * 16;
    int row = flat >> 9, colb = flat & 511;
    uint4 v = *(const uint4*)(lds + row * 528 + colb);
    *(uint4*)((char*)C + gRow0 * 512 + (size_t)flat) = v;
  }
  if (t < 4) partMax[t * 8192 + pmBase + bid] = sred[t];
  __threadfence();
  __syncthreads();
  if (t == 0) isLast = (atomicAdd(cnt, 1) == (int)gridDim.x - 1);
  __syncthreads();
  if (!isLast) return;
  __threadfence();
  float* red = (float*)&Xo[0][0];
  for (int h = 0; h < 4; ++h) {
    float m = -3.4e38f;
    for (int i = t; i < 8192; i += 256) m = fmaxf(m, partMax[h * 8192 + i]);
    red[t] = m;
    __syncthreads();
    for (int s = 128; s > 0; s >>= 1) {
      if (t < s) red[t] = fmaxf(red[t], red[t + s]);
      __syncthreads();
    }
    if (t == 0) Mh[h] = red[0];
    __syncthreads();
  }
}

// ---------------- u_raw[h] = sum_a exp(s-M)*keys[a]; last block -> attn ----
__global__ __launch_bounds__(256) void k_u2(
    const bf16_t* __restrict__ keys, const float* __restrict__ scores,
    const float* __restrict__ Mh,
    float* __restrict__ u, float* __restrict__ Ssum, int* __restrict__ cnt,
    const float* __restrict__ Wv, const float* __restrict__ bv,
    const float* __restrict__ Wo, const float* __restrict__ bo,
    bf16_t* __restrict__ attn_pad) {
  __shared__ float wl[4][512];
  __shared__ float uloc[8][4][256];     // 32 KiB
  __shared__ int isLast;
  int t = threadIdx.x;
  int a0 = blockIdx.x * 512;            // 512 blocks x 512 rows
#pragma unroll
  for (int i = 0; i < 8; ++i) {
    int e = i * 256 + t;                // 0..2047
    int h = e >> 9, rr = e & 511;
    wl[h][rr] = __expf(scores[(size_t)h * A_TOTAL + a0 + rr] - Mh[h]);
  }
  __syncthreads();
  // per-head exp-sum: wave h reduces wl[h][*]
  {
    int h = t >> 6, l = t & 63;
    float s = 0.f;
#pragma unroll
    for (int j = 0; j < 8; ++j) s += wl[h][l + j * 64];
#pragma unroll
    for (int o = 32; o > 0; o >>= 1) s += __shfl_xor(s, o);
    if (l == 0) atomicAdd(&Ssum[h], s);
  }
  int tc = t & 31, rh = t >> 5;         // 32 col-threads x 8 cols; 8 row groups
  float acc[4][8] = {};
  for (int rr = 0; rr < 64; ++rr) {
    int al = rh * 64 + rr;
    bf16x8 kv = *(const bf16x8*)(keys + (size_t)(a0 + al) * 256 + tc * 8);
    float f[8];
#pragma unroll
    for (int e = 0; e < 8; ++e) f[e] = (float)kv[e];
#pragma unroll
    for (int h = 0; h < 4; ++h) {
      float wv = wl[h][al];
#pragma unroll
      for (int e = 0; e < 8; ++e) acc[h][e] += wv * f[e];
    }
  }
#pragma unroll
  for (int h = 0; h < 4; ++h)
#pragma unroll
    for (int e = 0; e < 8; ++e) uloc[rh][h][tc * 8 + e] = acc[h][e];
  __syncthreads();
#pragma unroll
  for (int h = 0; h < 4; ++h) {
    float v = 0.f;
#pragma unroll
    for (int g = 0; g < 8; ++g) v += uloc[g][h][t];
    atomicAdd(&u[h * 256 + t], v);
  }
  __threadfence();
  __syncthreads();
  if (t == 0) isLast = (atomicAdd(cnt, 1) == (int)gridDim.x - 1);
  __syncthreads();
  if (!isLast) return;
  __threadfence();
  // ---- attention tail: ctx = (Wv . u_h)/S + bv ; attn = Wo . ctx + bo ----
  float* ctx = &wl[0][0];
  int h = t >> 6;
  {
    float invS = 1.0f / Ssum[h];
    const f32x4* row = (const f32x4*)(Wv + (size_t)t * 256);
    const f32x4* uh  = (const f32x4*)(u + h * 256);
    float acc2 = 0.f;
    for (int k = 0; k < 64; ++k) {
      f32x4 w = row[k];
      f32x4 x = uh[k];
      acc2 += w[0] * x[0] + w[1] * x[1] + w[2] * x[2] + w[3] * x[3];
    }
    ctx[t] = acc2 * invS + bv[t];
  }
  __syncthreads();
  {
    const f32x4* row = (const f32x4*)(Wo + (size_t)t * 256);
    float acc2 = 0.f;
    for (int k = 0; k < 64; ++k) {
      f32x4 w = row[k];
      acc2 += w[0] * ctx[4 * k] + w[1] * ctx[4 * k + 1] + w[2] * ctx[4 * k + 2] + w[3] * ctx[4 * k + 3];
    }
    float v = acc2 + bo[t];
    attn_pad[t] = (bf16_t)v;
#pragma unroll
    for (int i = 1; i < 16; ++i) attn_pad[i * 256 + t] = (bf16_t)0.f;
  }
}

// ---------------- logits + block max; last block -> Ml ---------------------
__global__ __launch_bounds__(256) void k_logits3(
    const bf16_t* __restrict__ keys, const bf16_t* __restrict__ attn_pad,
    float* __restrict__ out_logits, float* __restrict__ blockMax,
    int* __restrict__ cnt, float* __restrict__ Ml) {
  __shared__ float red[4];
  __shared__ float red2[256];
  __shared__ int isLast;
  int t = threadIdx.x;
  int w = t >> 6, lane = t & 63;
  int lm = lane & 15, q = lane >> 4;
  int m0 = blockIdx.x * 256 + w * 64;
  bf16x8 b[8];
#pragma unroll
  for (int kt = 0; kt < 8; ++kt)
    b[kt] = *(const bf16x8*)(attn_pad + lm * 256 + kt * 32 + q * 8);
  f32x4 acc[4] = {};
#pragma unroll
  for (int i = 0; i < 4; ++i) {
    const bf16_t* arow = keys + (size_t)(m0 + i * 16 + lm) * 256 + q * 8;
#pragma unroll
    for (int kt = 0; kt < 8; ++kt) {
      bf16x8 a = *(const bf16x8*)(arow + kt * 32);
      acc[i] = __builtin_amdgcn_mfma_f32_16x16x32_bf16(a, b[kt], acc[i], 0, 0, 0);
    }
  }
  float lmax = -3.4e38f;
  if (lm == 0) {
#pragma unroll
    for (int i = 0; i < 4; ++i) {
      *(f32x4*)(out_logits + m0 + i * 16 + q * 4) = acc[i];
#pragma unroll
      for (int rr = 0; rr < 4; ++rr) lmax = fmaxf(lmax, acc[i][rr]);
    }
  }
  float m1 = fmaxf(lmax, __shfl_xor(lmax, 16));
  float m2 = fmaxf(m1, __shfl_xor(m1, 32));
  if (lane == 0) red[w] = m2;
  __syncthreads();
  if (t == 0) {
    blockMax[blockIdx.x] = fmaxf(fmaxf(red[0], red[1]), fmaxf(red[2], red[3]));
    __threadfence();
    isLast = (atomicAdd(cnt, 1) == (int)gridDim.x - 1);
  }
  __syncthreads();
  if (!isLast) return;
  __threadfence();
  float m = -3.4e38f;
  for (int i = t; i < 1024; i += 256) m = fmaxf(m, blockMax[i]);
  red2[t] = m;
  __syncthreads();
  for (int s = 128; s > 0; s >>= 1) {
    if (t < s) red2[t] = fmaxf(red2[t], red2[t + s]);
    __syncthreads();
  }
  if (t == 0) Ml[0] = red2[0];
}

// ---------------- exp-sum partials; last block -> invSl --------------------
__global__ __launch_bounds__(256) void k_lsum2(const float* __restrict__ logits,
                                               const float* __restrict__ Ml,
                                               float* __restrict__ part,
                                               int* __restrict__ cnt,
                                               float* __restrict__ invSl) {
  int t = threadIdx.x, b = blockIdx.x;   // 512 blocks x 512 elems
  __shared__ float red[256];
  __shared__ int isLast;
  float m = Ml[0];
  float s = __expf(logits[b * 512 + t] - m) + __expf(logits[b * 512 + 256 + t] - m);
  red[t] = s;
  __syncthreads();
  for (int st = 128; st > 0; st >>= 1) {
    if (t < st) red[t] += red[t + st];
    __syncthreads();
  }
  if (t == 0) {
    part[b] = red[0];
    __threadfence();
    isLast = (atomicAdd(cnt, 1) == (int)gridDim.x - 1);
  }
  __syncthreads();
  if (!isLast) return;
  __threadfence();
  float v = part[t] + part[t + 256];
  red[t] = v;
  __syncthreads();
  for (int st = 128; st > 0; st >>= 1) {
    if (t < st) red[t] += red[t + st];
    __syncthreads();
  }
  if (t == 0) invSl[0] = 1.0f / red[0];
}

__global__ __launch_bounds__(256) void k_probs(const float* __restrict__ logits,
                                               const float* __restrict__ Ml,
                                               const float* __restrict__ invSl,
                                               float* __restrict__ probs) {
  int i = blockIdx.x * 256 + threadIdx.x;
  probs[i] = __expf(logits[i] - Ml[0]) * invSl[0];
}

// ===========================================================================
extern "C" void kernel_launch(void* const* d_in, const int* in_sizes, int n_in,
                              void* d_out, int out_size, void* d_ws, size_t ws_size,
                              hipStream_t stream) {
  const float* qubit_emb = (const float*)d_in[0];
  const float* qpu_emb   = (const float*)d_in[1];
  const float* gate_emb  = (const float*)d_in[2];
  const float* all_emb   = (const float*)d_in[3];
  const float* time_tab  = (const float*)d_in[4];
  const float* map_W1 = (const float*)d_in[5];
  const float* map_b1 = (const float*)d_in[6];
  const float* map_W2 = (const float*)d_in[7];
  const float* map_b2 = (const float*)d_in[8];
  const float* sch_W1 = (const float*)d_in[9];
  const float* sch_b1 = (const float*)d_in[10];
  const float* sch_W2 = (const float*)d_in[11];
  const float* sch_b2 = (const float*)d_in[12];
  const float* qg_W1 = (const float*)d_in[13];
  const float* qg_b1 = (const float*)d_in[14];
  const float* qg_W2 = (const float*)d_in[15];
  const float* qg_b2 = (const float*)d_in[16];
  const float* Wq = (const float*)d_in[17];
  const float* bq = (const float*)d_in[18];
  const float* Wk = (const float*)d_in[19];
  // d_in[20] = attn_bk: per-head constant, softmax-invariant -> unused
  const float* Wv = (const float*)d_in[21];
  const float* bv = (const float*)d_in[22];
  const float* Wo = (const float*)d_in[23];
  const float* bo = (const float*)d_in[24];
  const int* map_qubit  = (const int*)d_in[25];
  const int* map_qpu    = (const int*)d_in[26];
  const int* sched_gate = (const int*)d_in[27];
  const int* sched_time = (const int*)d_in[28];
  (void)in_sizes; (void)n_in; (void)out_size;

  char* ws = (char*)d_ws;
  size_t off = 0;
  auto alloc = [&](size_t b) { size_t r = off; off += (b + 255) & ~(size_t)255; return r; };
  size_t KEYS  = alloc((size_t)A_TOTAL * 256 * 2);   // bf16 keys
  size_t PQ    = alloc((size_t)65536 * 256 * 2);     // bf16 qubit proj
  size_t PG    = alloc((size_t)65536 * 256 * 2);     // bf16 gate proj
  size_t PP    = alloc((size_t)128 * 256 * 2);       // bf16 qpu proj (+b1)
  size_t PT    = alloc((size_t)1024 * 256 * 2);      // bf16 time proj (+b1)
  size_t W1B   = alloc((size_t)4 * 65536 * 2);       // bf16 W1 slices
  size_t WEXT  = alloc((size_t)2 * 272 * 256 * 2);   // bf16 extended W2 (+qw)
  size_t SCORE = alloc((size_t)4 * A_TOTAL * 4);     // f32 scores [4][A]
  size_t MPART = alloc((size_t)512 * 256 * 4);       // mean partials
  size_t APAD  = alloc((size_t)16 * 256 * 2);        // bf16 attn_out padded
  size_t U     = alloc(4 * 256 * 4);                 // 4096 B
  size_t SSUM  = alloc(4 * 4);                       // +256 B block
  size_t CNT   = alloc(4 * 4);                       // +256 B block
  size_t PMAX  = alloc(4 * 8192 * 4);
  size_t MH    = alloc(4 * 4);
  size_t BMAX  = alloc(1024 * 4);
  size_t ML    = alloc(4);
  size_t SLINV = alloc(4);
  size_t LPART = alloc(512 * 4);
  if (off > ws_size) return;  // insufficient scratch -> loud validation fail

  bf16_t* keysP  = (bf16_t*)(ws + KEYS);
  bf16_t* pqP    = (bf16_t*)(ws + PQ);
  bf16_t* pgP    = (bf16_t*)(ws + PG);
  bf16_t* ppP    = (bf16_t*)(ws + PP);
  bf16_t* ptP    = (bf16_t*)(ws + PT);
  bf16_t* w1bP   = (bf16_t*)(ws + W1B);
  bf16_t* wextP  = (bf16_t*)(ws + WEXT);
  float*  scoreP = (float*)(ws + SCORE);
  float*  mpartP = (float*)(ws + MPART);
  bf16_t* apadP  = (bf16_t*)(ws + APAD);
  float*  uP     = (float*)(ws + U);
  float*  ssumP  = (float*)(ws + SSUM);
  int*    cntP   = (int*)(ws + CNT);
  float*  pmaxP  = (float*)(ws + PMAX);
  float*  mhP    = (float*)(ws + MH);
  float*  bmaxP  = (float*)(ws + BMAX);
  float*  mlP    = (float*)(ws + ML);
  float*  slinvP = (float*)(ws + SLINV);
  float*  lpartP = (float*)(ws + LPART);

  float* probsOut  = (float*)d_out;
  float* logitsOut = probsOut + A_TOTAL;

  // zero u, Ssum, cnt (contiguous alloc blocks: 4096 + 256 + 256)
  hipMemsetAsync(uP, 0, 4608, stream);

  k_prep<<<1568, 256, 0, stream>>>(map_W1, sch_W1, w1bP, map_W2, sch_W2, wextP);
  k_mean<<<512, 256, 0, stream>>>(all_emb, mpartP);
  k_front<<<1, 256, 0, stream>>>(mpartP, qg_W1, qg_b1, qg_W2, qg_b2,
                                 Wq, bq, Wk, map_W2, sch_W2, wextP);

  // table projections (layer-1 halves): qubit+gate merged, qpu+time merged
  gemm_direct3<<<1024, 512, 0, stream>>>(
      qubit_emb, 65536, w1bP + 0 * 65536, nullptr, pqP, 512,
      gate_emb,  65536, w1bP + 2 * 65536, nullptr, pgP);
  gemm_direct3<<<9, 512, 0, stream>>>(
      qpu_emb, 64,   w1bP + 1 * 65536, map_b1, ppP, 1,
      time_tab, 1000, w1bP + 3 * 65536, sch_b1, ptP);

  // keys + fused scores (both halves; last block reduces Mh)
  gemm_gather4<<<8192, 256, 0, stream>>>(
      pqP, ppP, map_qubit, map_qpu, wextP, map_b2,
      pgP, ptP, sched_gate, sched_time, wextP + 272 * 256, sch_b2,
      keysP, scoreP, pmaxP, cntP + 0, mhP);

  // weighted key sum (unnormalized) + Ssum; last block does attn matvecs
  k_u2<<<512, 256, 0, stream>>>(keysP, scoreP, mhP, uP, ssumP, cntP + 1,
                                Wv, bv, Wo, bo, apadP);

  // logits + global softmax
  k_logits3<<<1024, 256, 0, stream>>>(keysP, apadP, logitsOut, bmaxP,
                                      cntP + 2, mlP);
  k_lsum2<<<512, 256, 0, stream>>>(logitsOut, mlP, lpartP, cntP + 3, slinvP);
  k_probs<<<1024, 256, 0, stream>>>(logitsOut, mlP, slinvP, probsOut);
}

// Round 3
// 840.747 us; speedup vs baseline: 2.1932x; 2.1932x over previous
//
#include <hip/hip_runtime.h>
#include <cstdint>
#include <cstddef>

typedef __bf16 bf16_t;
typedef __bf16 bf16x8 __attribute__((ext_vector_type(8)));
typedef __bf16 bf16x4 __attribute__((ext_vector_type(4)));
typedef __bf16 bf16x2 __attribute__((ext_vector_type(2)));
typedef float f32x4 __attribute__((ext_vector_type(4)));

#define A_TOTAL 262144
#define NMAP    131072

// ---------------- W1 slices f32 -> bf16 ------------------------------------
__global__ __launch_bounds__(256) void k_w1b16(
    const float* __restrict__ mW1, const float* __restrict__ sW1,
    bf16_t* __restrict__ dst) {
  int e = blockIdx.x * 256 + threadIdx.x;     // 0..262143
  int slice = e >> 16, idx = e & 65535;
  int n = idx >> 8, k = idx & 255;
  float v;
  switch (slice) {
    case 0:  v = mW1[n * 512 + k]; break;
    case 1:  v = mW1[n * 512 + 256 + k]; break;
    case 2:  v = sW1[n * 512 + k]; break;
    default: v = sW1[n * 512 + 256 + k]; break;
  }
  dst[e] = (bf16_t)v;
}

// ---------------- W2 -> extended weights [272][256] per table --------------
__global__ __launch_bounds__(256) void k_w2ext(
    const float* __restrict__ mW2, const float* __restrict__ sW2,
    bf16_t* __restrict__ wext) {
  int row = blockIdx.x, tab = blockIdx.y, k = threadIdx.x;
  const float* W2 = tab ? sW2 : mW2;
  bf16_t v = (row < 256) ? (bf16_t)W2[row * 256 + k] : (bf16_t)0.f;
  wext[(size_t)tab * 272 * 256 + (size_t)row * 256 + k] = v;
}

// ---------------- column partial sums of all_embeddings [131072][256] ------
__global__ __launch_bounds__(256) void k_mean(const float* __restrict__ A,
                                              float* __restrict__ part) {
  int t = threadIdx.x, b = blockIdx.x;        // 256 blocks x 512 rows
  const float* base = A + (size_t)b * 512 * 256 + t;
  float s = 0.f;
  for (int r = 0; r < 512; ++r) s += base[(size_t)r * 256];
  part[b * 256 + t] = s;
}

// ---------------- g -> query MLP -> q -> qk -> qw rows of Wext -------------
__global__ __launch_bounds__(256) void k_front(
    const float* __restrict__ meanPart,
    const float* __restrict__ qgW1, const float* __restrict__ qgb1,
    const float* __restrict__ qgW2, const float* __restrict__ qgb2,
    const float* __restrict__ Wq,  const float* __restrict__ bq,
    const float* __restrict__ Wk,
    const float* __restrict__ mW2, const float* __restrict__ sW2,
    bf16_t* __restrict__ wext) {
  __shared__ float g[256], h1[256], qry[256], qv[256];
  __shared__ float qks[4][256];
  int t = threadIdx.x;
  float s = 0.f;
  for (int b = 0; b < 256; ++b) s += meanPart[b * 256 + t];
  g[t] = s * (1.0f / 131072.0f);
  __syncthreads();
  {
    const f32x4* row = (const f32x4*)(qgW1 + (size_t)t * 256);
    float acc = 0.f;
    for (int k = 0; k < 64; ++k) {
      f32x4 w = row[k];
      acc += w[0] * g[4 * k] + w[1] * g[4 * k + 1] + w[2] * g[4 * k + 2] + w[3] * g[4 * k + 3];
    }
    h1[t] = fmaxf(acc + qgb1[t], 0.f);
  }
  __syncthreads();
  {
    const f32x4* row = (const f32x4*)(qgW2 + (size_t)t * 256);
    float acc = 0.f;
    for (int k = 0; k < 64; ++k) {
      f32x4 w = row[k];
      acc += w[0] * h1[4 * k] + w[1] * h1[4 * k + 1] + w[2] * h1[4 * k + 2] + w[3] * h1[4 * k + 3];
    }
    qry[t] = acc + qgb2[t];
  }
  __syncthreads();
  {
    const f32x4* row = (const f32x4*)(Wq + (size_t)t * 256);
    float acc = 0.f;
    for (int k = 0; k < 64; ++k) {
      f32x4 w = row[k];
      acc += w[0] * qry[4 * k] + w[1] * qry[4 * k + 1] + w[2] * qry[4 * k + 2] + w[3] * qry[4 * k + 3];
    }
    qv[t] = acc + bq[t];
  }
  __syncthreads();
  for (int h = 0; h < 4; ++h) {
    float acc = 0.f;
    for (int d = 0; d < 64; ++d) acc += qv[h * 64 + d] * Wk[(size_t)(h * 64 + d) * 256 + t];
    qks[h][t] = acc * 0.125f;
  }
  __syncthreads();
  for (int tab = 0; tab < 2; ++tab) {
    const float* W2 = tab ? sW2 : mW2;
    float acc0 = 0.f, acc1 = 0.f, acc2 = 0.f, acc3 = 0.f;
    for (int n = 0; n < 256; ++n) {
      float wv = W2[(size_t)n * 256 + t];
      acc0 += qks[0][n] * wv;
      acc1 += qks[1][n] * wv;
      acc2 += qks[2][n] * wv;
      acc3 += qks[3][n] * wv;
    }
    bf16_t* dst = wext + (size_t)tab * 272 * 256;
    dst[(256 + 0) * 256 + t] = (bf16_t)acc0;
    dst[(256 + 1) * 256 + t] = (bf16_t)acc1;
    dst[(256 + 2) * 256 + t] = (bf16_t)acc2;
    dst[(256 + 3) * 256 + t] = (bf16_t)acc3;
  }
}

// ---------------- GEMM (direct, merged 2 problem halves) -------------------
__global__ __launch_bounds__(512, 4) void gemm_direct3(
    const float* __restrict__ A0, int M0, const bf16_t* __restrict__ W0,
    const float* __restrict__ b0, bf16_t* __restrict__ C0, int split,
    const float* __restrict__ A1, int M1, const bf16_t* __restrict__ W1,
    const float* __restrict__ b1, bf16_t* __restrict__ C1) {
  __shared__ __align__(16) bf16_t Xo[128][264];   // 67584 B
  int blk = blockIdx.x;
  const float* A; int M; const bf16_t* W; const float* bias; bf16_t* C; int bid;
  if (blk < split) { A = A0; M = M0; W = W0; bias = b0; C = C0; bid = blk; }
  else             { A = A1; M = M1; W = W1; bias = b1; C = C1; bid = blk - split; }
  int t = threadIdx.x;
  int w = t >> 6, lane = t & 63;
  int lm = lane & 15, q = lane >> 4;
  int mloc0 = (w & 1) * 64;
  int m0 = bid * 128 + mloc0;
  int c0 = (w >> 1) * 64;
  int rows[4];
#pragma unroll
  for (int i = 0; i < 4; ++i) {
    int m = m0 + i * 16 + lm;
    rows[i] = m < M ? m : M - 1;
  }
  f32x4 acc[4][4] = {};
#pragma unroll
  for (int kt = 0; kt < 8; ++kt) {
    int k0 = kt * 32 + q * 8;
    bf16x8 b[4];
#pragma unroll
    for (int j = 0; j < 4; ++j)
      b[j] = *(const bf16x8*)(W + (size_t)(c0 + j * 16 + lm) * 256 + k0);
#pragma unroll
    for (int i = 0; i < 4; ++i) {
      const float* src = A + (size_t)rows[i] * 256 + k0;
      f32x4 lo = *(const f32x4*)src;
      f32x4 hi = *(const f32x4*)(src + 4);
      bf16x8 a;
#pragma unroll
      for (int x = 0; x < 4; ++x) { a[x] = (bf16_t)lo[x]; a[x + 4] = (bf16_t)hi[x]; }
#pragma unroll
      for (int j = 0; j < 4; ++j)
        acc[i][j] = __builtin_amdgcn_mfma_f32_16x16x32_bf16(a, b[j], acc[i][j], 0, 0, 0);
    }
  }
#pragma unroll
  for (int j = 0; j < 4; ++j) {
    int col = c0 + j * 16 + lm;
    float bb = bias ? bias[col] : 0.f;
#pragma unroll
    for (int i = 0; i < 4; ++i)
#pragma unroll
      for (int r = 0; r < 4; ++r)
        Xo[mloc0 + i * 16 + q * 4 + r][col] = (bf16_t)(acc[i][j][r] + bb);
  }
  __syncthreads();
  size_t tile0 = (size_t)bid * 128;
  const char* lds = (const char*)&Xo[0][0];
#pragma unroll
  for (int s = 0; s < 8; ++s) {
    int flat = s * 8192 + t * 16;
    int row = flat >> 9, colb = flat & 511;
    if (tile0 + (size_t)row < (size_t)M) {
      uint4 v = *(const uint4*)(lds + row * 528 + colb);
      *(uint4*)((char*)C + tile0 * 512 + (size_t)flat) = v;
    }
  }
}

// ---------------- GEMM (gather, pipelined 4 tiles/block) + fused scores ----
// 256 thr = 4 waves (col split). 32-row tiles; tile t+1's idx+gather loads
// (reg-held, 16-deep ILP) are issued before tile t's MFMA phase, so HBM/L3
// latency hides under compute. Tiles per block: map lo/hi, sched lo/hi.
__global__ __launch_bounds__(256, 4) void gemm_gather5(
    const bf16_t* __restrict__ Pa0, const bf16_t* __restrict__ Pb0,
    const int* __restrict__ idxA0, const int* __restrict__ idxB0,
    const bf16_t* __restrict__ Wext0, const float* __restrict__ bias0,
    const bf16_t* __restrict__ Pa1, const bf16_t* __restrict__ Pb1,
    const int* __restrict__ idxA1, const int* __restrict__ idxB1,
    const bf16_t* __restrict__ Wext1, const float* __restrict__ bias1,
    bf16_t* __restrict__ C,
    float* __restrict__ scores, float* __restrict__ partMax) {
  __shared__ __align__(16) bf16_t X[32][264];    // 16.9 KB, reused for output
  __shared__ float sred[4];
  int t = threadIdx.x;
  int w = t >> 6, lane = t & 63;
  int lm = lane & 15, q = lane >> 4;
  int cw = w * 64;
  int r = t >> 3, qa = t & 7;        // 8 threads per row, 128B runs
  int b = blockIdx.x;                // 2048 blocks

  bf16x8 va[4], vb[4];
  // ---- prologue: stage loads for tile 0 (map half, rows b*32)
  {
    int ia = idxA0[b * 32 + r], ib = idxB0[b * 32 + r];
    const bf16_t* paRow = Pa0 + (size_t)ia * 256;
    const bf16_t* pbRow = Pb0 + (size_t)ib * 256;
#pragma unroll
    for (int s = 0; s < 4; ++s) {
      int ch = s * 8 + qa;
      va[s] = *(const bf16x8*)(paRow + ch * 8);
      vb[s] = *(const bf16x8*)(pbRow + ch * 8);
    }
  }
  int ian = 0, ibn = 0;

#pragma unroll
  for (int it = 0; it < 4; ++it) {
    const int half = it >> 1;
    const int bid  = b + (it & 1) * 2048;
    const int row0 = bid * 32;
    const bf16_t* Wext = half ? Wext1 : Wext0;
    const float*  bias = half ? bias1 : bias0;

    // issue idx loads for next tile (completes during stage+barrier)
    if (it < 3) {
      const int bidn = b + ((it + 1) & 1) * 2048;
      const int* iA = ((it + 1) < 2) ? idxA0 : idxA1;
      const int* iB = ((it + 1) < 2) ? idxB0 : idxB1;
      ian = iA[bidn * 32 + r];
      ibn = iB[bidn * 32 + r];
    }
    if (it) __syncthreads();           // prev tile's copy reads done
    // stage current tile into X (compiler waits va/vb here)
#pragma unroll
    for (int s = 0; s < 4; ++s) {
      int ch = s * 8 + qa;
      bf16x8 x;
#pragma unroll
      for (int e = 0; e < 8; ++e)
        x[e] = (bf16_t)fmaxf((float)va[s][e] + (float)vb[s][e], 0.f);
      *(bf16x8*)&X[r][ch * 8] = x;
    }
    __syncthreads();                   // X ready
    // issue next tile's gather loads NOW -> in flight across MFMA phase
    if (it < 3) {
      const bf16_t* Pan = ((it + 1) < 2) ? Pa0 : Pa1;
      const bf16_t* Pbn = ((it + 1) < 2) ? Pb0 : Pb1;
      const bf16_t* paRow = Pan + (size_t)ian * 256;
      const bf16_t* pbRow = Pbn + (size_t)ibn * 256;
#pragma unroll
      for (int s = 0; s < 4; ++s) {
        int ch = s * 8 + qa;
        va[s] = *(const bf16x8*)(paRow + ch * 8);
        vb[s] = *(const bf16x8*)(pbRow + ch * 8);
      }
    }
    // MFMA phase
    f32x4 acc[2][4] = {};
    f32x4 accs[2] = {};
    bool doScore = (w == 0);
#pragma unroll
    for (int kt = 0; kt < 8; ++kt) {
      int kl = kt * 32 + q * 8;
      bf16x8 a[2];
#pragma unroll
      for (int i = 0; i < 2; ++i)
        a[i] = *(const bf16x8*)&X[i * 16 + lm][kl];
#pragma unroll
      for (int j = 0; j < 4; ++j) {
        bf16x8 bw = *(const bf16x8*)(Wext + (size_t)(cw + j * 16 + lm) * 256 + kl);
#pragma unroll
        for (int i = 0; i < 2; ++i)
          acc[i][j] = __builtin_amdgcn_mfma_f32_16x16x32_bf16(a[i], bw, acc[i][j], 0, 0, 0);
      }
      if (doScore) {
        bf16x8 bs = *(const bf16x8*)(Wext + (size_t)(256 + lm) * 256 + kl);
#pragma unroll
        for (int i = 0; i < 2; ++i)
          accs[i] = __builtin_amdgcn_mfma_f32_16x16x32_bf16(a[i], bs, accs[i], 0, 0, 0);
      }
    }
    __syncthreads();                   // all X reads done; reuse X for output
    // stage bias-added bf16 keys back into X
#pragma unroll
    for (int j = 0; j < 4; ++j) {
      int col = cw + j * 16 + lm;
      float bb = bias[col];
#pragma unroll
      for (int i = 0; i < 2; ++i)
#pragma unroll
        for (int rr = 0; rr < 4; ++rr)
          X[i * 16 + q * 4 + rr][col] = (bf16_t)(acc[i][j][rr] + bb);
    }
    // scores epilogue (wave 0; lanes lm<4 hold head lm)
    float hmax = -3.4e38f;
    if (doScore) {
      if (lm < 4) {
#pragma unroll
        for (int i = 0; i < 2; ++i)
#pragma unroll
          for (int rr = 0; rr < 4; ++rr) {
            int m = i * 16 + q * 4 + rr;
            float v = accs[i][rr];
            scores[(size_t)lm * A_TOTAL + half * NMAP + row0 + m] = v;
            hmax = fmaxf(hmax, v);
          }
      }
      float m1 = fmaxf(hmax, __shfl_xor(hmax, 16));
      float m2 = fmaxf(m1, __shfl_xor(m1, 32));
      if (lane < 4) sred[lane] = m2;
    }
    __syncthreads();                   // keys staged + sred ready
    // flat coalesced write: 32 rows x 512 B
    size_t gRow0 = (size_t)(half * NMAP + row0);
    const char* lds = (const char*)&X[0][0];
#pragma unroll
    for (int s = 0; s < 4; ++s) {
      int flat = s * 4096 + t * 16;
      int row = flat >> 9, colb = flat & 511;
      uint4 v = *(const uint4*)(lds + row * 528 + colb);
      *(uint4*)((char*)C + gRow0 * 512 + (size_t)flat) = v;
    }
    if (t < 4) partMax[t * 8192 + half * 4096 + bid] = sred[t];
  }
}

// ---------------- per-head max over 8192 tile partials ---------------------
__global__ __launch_bounds__(256) void k_smax2(const float* __restrict__ pM,
                                               float* __restrict__ Mh) {
  int t = threadIdx.x;
  __shared__ float red[256];
  for (int h = 0; h < 4; ++h) {
    float m = -3.4e38f;
    for (int i = t; i < 8192; i += 256) m = fmaxf(m, pM[h * 8192 + i]);
    red[t] = m;
    __syncthreads();
    for (int s = 128; s > 0; s >>= 1) {
      if (t < s) red[t] = fmaxf(red[t], red[t + s]);
      __syncthreads();
    }
    if (t == 0) Mh[h] = red[0];
    __syncthreads();
  }
}

__global__ __launch_bounds__(256) void k_ssum(const float* __restrict__ scores,
                                              const float* __restrict__ Mh,
                                              float* __restrict__ part) {
  int b = blockIdx.x, t = threadIdx.x;    // 256 blocks, head = b>>6
  float m = Mh[b >> 6];
  const float* base = scores + (size_t)b * 4096;
  float s = 0.f;
  for (int i = 0; i < 16; ++i) s += __expf(base[i * 256 + t] - m);
  __shared__ float red[256];
  red[t] = s;
  __syncthreads();
  for (int st = 128; st > 0; st >>= 1) {
    if (t < st) red[t] += red[t + st];
    __syncthreads();
  }
  if (t == 0) part[b] = red[0];
}

__global__ __launch_bounds__(256) void k_ssum2(const float* __restrict__ part,
                                               float* __restrict__ invS) {
  int t = threadIdx.x;
  __shared__ float red[256];
  red[t] = part[t];
  __syncthreads();
  for (int s = 32; s > 0; s >>= 1) {
    if ((t & 63) < s) red[t] += red[t + s];
    __syncthreads();
  }
  if ((t & 63) == 0) invS[t >> 6] = 1.0f / red[t];
}

// ---------------- u[h] = sum_a w[h,a] * keys[a] (bf16x8 loads) -------------
__global__ __launch_bounds__(256) void k_u(
    const bf16_t* __restrict__ keys, const float* __restrict__ scores,
    const float* __restrict__ Mh, const float* __restrict__ invS,
    float* __restrict__ u) {
  __shared__ float wl[4][512];
  __shared__ float uloc[8][4][256];     // 32 KiB
  int t = threadIdx.x;
  int a0 = blockIdx.x * 512;            // 512 blocks x 512 rows
#pragma unroll
  for (int i = 0; i < 8; ++i) {
    int e = i * 256 + t;                // 0..2047
    int h = e >> 9, rr = e & 511;
    wl[h][rr] = __expf(scores[(size_t)h * A_TOTAL + a0 + rr] - Mh[h]) * invS[h];
  }
  __syncthreads();
  int tc = t & 31, rh = t >> 5;         // 32 col-threads x 8 cols; 8 row groups
  float acc[4][8] = {};
  for (int rr = 0; rr < 64; ++rr) {
    int al = rh * 64 + rr;
    bf16x8 kv = *(const bf16x8*)(keys + (size_t)(a0 + al) * 256 + tc * 8);
    float f[8];
#pragma unroll
    for (int e = 0; e < 8; ++e) f[e] = (float)kv[e];
#pragma unroll
    for (int h = 0; h < 4; ++h) {
      float wv = wl[h][al];
#pragma unroll
      for (int e = 0; e < 8; ++e) acc[h][e] += wv * f[e];
    }
  }
#pragma unroll
  for (int h = 0; h < 4; ++h)
#pragma unroll
    for (int e = 0; e < 8; ++e) uloc[rh][h][tc * 8 + e] = acc[h][e];
  __syncthreads();
#pragma unroll
  for (int h = 0; h < 4; ++h) {
    float v = 0.f;
#pragma unroll
    for (int g = 0; g < 8; ++g) v += uloc[g][h][t];
    atomicAdd(&u[h * 256 + t], v);
  }
}

// ---------------- ctx = u @ Wv_h^T + bv ; attn_out = ctx @ Wo^T + bo -------
__global__ __launch_bounds__(256) void k_attn(
    const float* __restrict__ u, const float* __restrict__ Wv,
    const float* __restrict__ bv, const float* __restrict__ Wo,
    const float* __restrict__ bo, float* __restrict__ attn_out,
    bf16_t* __restrict__ attn_pad) {
  __shared__ float ctx[256];
  int t = threadIdx.x;
  int h = t >> 6;
  const float* uh = u + h * 256;
  {
    const f32x4* row = (const f32x4*)(Wv + (size_t)t * 256);
    float acc = 0.f;
    for (int k = 0; k < 64; ++k) {
      f32x4 w = row[k];
      acc += w[0] * uh[4 * k] + w[1] * uh[4 * k + 1] + w[2] * uh[4 * k + 2] + w[3] * uh[4 * k + 3];
    }
    ctx[t] = acc + bv[t];
  }
  __syncthreads();
  {
    const f32x4* row = (const f32x4*)(Wo + (size_t)t * 256);
    float acc = 0.f;
    for (int k = 0; k < 64; ++k) {
      f32x4 w = row[k];
      acc += w[0] * ctx[4 * k] + w[1] * ctx[4 * k + 1] + w[2] * ctx[4 * k + 2] + w[3] * ctx[4 * k + 3];
    }
    float v = acc + bo[t];
    attn_out[t] = v;
    attn_pad[t] = (bf16_t)v;
#pragma unroll
    for (int i = 1; i < 16; ++i) attn_pad[i * 256 + t] = (bf16_t)0.f;
  }
}

// ---------------- logits[a] = keys[a] . attn_out (MFMA) + block max --------
__global__ __launch_bounds__(256) void k_logits2(
    const bf16_t* __restrict__ keys, const bf16_t* __restrict__ attn_pad,
    float* __restrict__ out_logits, float* __restrict__ blockMax) {
  int t = threadIdx.x;
  int w = t >> 6, lane = t & 63;
  int lm = lane & 15, q = lane >> 4;
  int m0 = blockIdx.x * 256 + w * 64;
  bf16x8 b[8];
#pragma unroll
  for (int kt = 0; kt < 8; ++kt)
    b[kt] = *(const bf16x8*)(attn_pad + lm * 256 + kt * 32 + q * 8);
  f32x4 acc[4] = {};
#pragma unroll
  for (int i = 0; i < 4; ++i) {
    const bf16_t* arow = keys + (size_t)(m0 + i * 16 + lm) * 256 + q * 8;
#pragma unroll
    for (int kt = 0; kt < 8; ++kt) {
      bf16x8 a = *(const bf16x8*)(arow + kt * 32);
      acc[i] = __builtin_amdgcn_mfma_f32_16x16x32_bf16(a, b[kt], acc[i], 0, 0, 0);
    }
  }
  float lmax = -3.4e38f;
  if (lm == 0) {
#pragma unroll
    for (int i = 0; i < 4; ++i) {
      *(f32x4*)(out_logits + m0 + i * 16 + q * 4) = acc[i];
#pragma unroll
      for (int rr = 0; rr < 4; ++rr) lmax = fmaxf(lmax, acc[i][rr]);
    }
  }
  float m1 = fmaxf(lmax, __shfl_xor(lmax, 16));
  float m2 = fmaxf(m1, __shfl_xor(m1, 32));
  __shared__ float red[4];
  if (lane == 0) red[w] = m2;
  __syncthreads();
  if (t == 0)
    blockMax[blockIdx.x] = fmaxf(fmaxf(red[0], red[1]), fmaxf(red[2], red[3]));
}

__global__ __launch_bounds__(256) void k_lred1(const float* __restrict__ bm,
                                               float* __restrict__ Ml) {
  int t = threadIdx.x;
  float m = -3.4e38f;
  for (int i = t; i < 1024; i += 256) m = fmaxf(m, bm[i]);
  __shared__ float red[256];
  red[t] = m;
  __syncthreads();
  for (int s = 128; s > 0; s >>= 1) {
    if (t < s) red[t] = fmaxf(red[t], red[t + s]);
    __syncthreads();
  }
  if (t == 0) Ml[0] = red[0];
}

__global__ __launch_bounds__(256) void k_lsum(const float* __restrict__ logits,
                                              const float* __restrict__ Ml,
                                              float* __restrict__ part) {
  int t = threadIdx.x, b = blockIdx.x;   // 512 blocks x 512 elems
  float m = Ml[0];
  float s = __expf(logits[b * 512 + t] - m) + __expf(logits[b * 512 + 256 + t] - m);
  __shared__ float red[256];
  red[t] = s;
  __syncthreads();
  for (int st = 128; st > 0; st >>= 1) {
    if (t < st) red[t] += red[t + st];
    __syncthreads();
  }
  if (t == 0) part[b] = red[0];
}

__global__ __launch_bounds__(256) void k_lred2(const float* __restrict__ part,
                                               float* __restrict__ invSl) {
  int t = threadIdx.x;
  float s = part[t] + part[t + 256];
  __shared__ float red[256];
  red[t] = s;
  __syncthreads();
  for (int st = 128; st > 0; st >>= 1) {
    if (t < st) red[t] += red[t + st];
    __syncthreads();
  }
  if (t == 0) invSl[0] = 1.0f / red[0];
}

__global__ __launch_bounds__(256) void k_probs(const float* __restrict__ logits,
                                               const float* __restrict__ Ml,
                                               const float* __restrict__ invSl,
                                               float* __restrict__ probs) {
  int i = blockIdx.x * 256 + threadIdx.x;
  probs[i] = __expf(logits[i] - Ml[0]) * invSl[0];
}

// ===========================================================================
extern "C" void kernel_launch(void* const* d_in, const int* in_sizes, int n_in,
                              void* d_out, int out_size, void* d_ws, size_t ws_size,
                              hipStream_t stream) {
  const float* qubit_emb = (const float*)d_in[0];
  const float* qpu_emb   = (const float*)d_in[1];
  const float* gate_emb  = (const float*)d_in[2];
  const float* all_emb   = (const float*)d_in[3];
  const float* time_tab  = (const float*)d_in[4];
  const float* map_W1 = (const float*)d_in[5];
  const float* map_b1 = (const float*)d_in[6];
  const float* map_W2 = (const float*)d_in[7];
  const float* map_b2 = (const float*)d_in[8];
  const float* sch_W1 = (const float*)d_in[9];
  const float* sch_b1 = (const float*)d_in[10];
  const float* sch_W2 = (const float*)d_in[11];
  const float* sch_b2 = (const float*)d_in[12];
  const float* qg_W1 = (const float*)d_in[13];
  const float* qg_b1 = (const float*)d_in[14];
  const float* qg_W2 = (const float*)d_in[15];
  const float* qg_b2 = (const float*)d_in[16];
  const float* Wq = (const float*)d_in[17];
  const float* bq = (const float*)d_in[18];
  const float* Wk = (const float*)d_in[19];
  // d_in[20] = attn_bk: per-head constant, softmax-invariant -> unused
  const float* Wv = (const float*)d_in[21];
  const float* bv = (const float*)d_in[22];
  const float* Wo = (const float*)d_in[23];
  const float* bo = (const float*)d_in[24];
  const int* map_qubit  = (const int*)d_in[25];
  const int* map_qpu    = (const int*)d_in[26];
  const int* sched_gate = (const int*)d_in[27];
  const int* sched_time = (const int*)d_in[28];
  (void)in_sizes; (void)n_in; (void)out_size;

  char* ws = (char*)d_ws;
  size_t off = 0;
  auto alloc = [&](size_t b) { size_t r = off; off += (b + 255) & ~(size_t)255; return r; };
  size_t KEYS  = alloc((size_t)A_TOTAL * 256 * 2);   // bf16 keys
  size_t PQ    = alloc((size_t)65536 * 256 * 2);     // bf16 qubit proj
  size_t PG    = alloc((size_t)65536 * 256 * 2);     // bf16 gate proj
  size_t PP    = alloc((size_t)128 * 256 * 2);       // bf16 qpu proj (+b1)
  size_t PT    = alloc((size_t)1024 * 256 * 2);      // bf16 time proj (+b1)
  size_t W1B   = alloc((size_t)4 * 65536 * 2);       // bf16 W1 slices
  size_t WEXT  = alloc((size_t)2 * 272 * 256 * 2);   // bf16 extended W2 (+qw)
  size_t SCORE = alloc((size_t)4 * A_TOTAL * 4);     // f32 scores [4][A]
  size_t MPART = alloc((size_t)256 * 256 * 4);       // mean partials
  size_t APAD  = alloc((size_t)16 * 256 * 2);        // bf16 attn_out padded
  size_t ATTN  = alloc(256 * 4);
  size_t U     = alloc(4 * 256 * 4);
  size_t PMAX  = alloc(4 * 8192 * 4);
  size_t MH    = alloc(4 * 4);
  size_t SINV  = alloc(4 * 4);
  size_t BMAX  = alloc(1024 * 4);
  size_t ML    = alloc(4);
  size_t SLINV = alloc(4);
  size_t LPART = alloc(512 * 4);
  size_t SPART = alloc(256 * 4);
  if (off > ws_size) return;  // insufficient scratch -> loud validation fail

  bf16_t* keysP  = (bf16_t*)(ws + KEYS);
  bf16_t* pqP    = (bf16_t*)(ws + PQ);
  bf16_t* pgP    = (bf16_t*)(ws + PG);
  bf16_t* ppP    = (bf16_t*)(ws + PP);
  bf16_t* ptP    = (bf16_t*)(ws + PT);
  bf16_t* w1bP   = (bf16_t*)(ws + W1B);
  bf16_t* wextP  = (bf16_t*)(ws + WEXT);
  float*  scoreP = (float*)(ws + SCORE);
  float*  mpartP = (float*)(ws + MPART);
  bf16_t* apadP  = (bf16_t*)(ws + APAD);
  float*  attnP  = (float*)(ws + ATTN);
  float*  uP     = (float*)(ws + U);
  float*  pmaxP  = (float*)(ws + PMAX);
  float*  mhP    = (float*)(ws + MH);
  float*  sinvP  = (float*)(ws + SINV);
  float*  bmaxP  = (float*)(ws + BMAX);
  float*  mlP    = (float*)(ws + ML);
  float*  slinvP = (float*)(ws + SLINV);
  float*  lpartP = (float*)(ws + LPART);
  float*  spartP = (float*)(ws + SPART);

  float* probsOut  = (float*)d_out;
  float* logitsOut = probsOut + A_TOTAL;

  hipMemsetAsync(uP, 0, 4 * 256 * 4, stream);

  k_w1b16<<<1024, 256, 0, stream>>>(map_W1, sch_W1, w1bP);
  k_w2ext<<<dim3(272, 2), 256, 0, stream>>>(map_W2, sch_W2, wextP);
  k_mean<<<256, 256, 0, stream>>>(all_emb, mpartP);
  k_front<<<1, 256, 0, stream>>>(mpartP, qg_W1, qg_b1, qg_W2, qg_b2,
                                 Wq, bq, Wk, map_W2, sch_W2, wextP);

  // table projections (layer-1 halves): qubit+gate merged, qpu+time merged
  gemm_direct3<<<1024, 512, 0, stream>>>(
      qubit_emb, 65536, w1bP + 0 * 65536, nullptr, pqP, 512,
      gate_emb,  65536, w1bP + 2 * 65536, nullptr, pgP);
  gemm_direct3<<<9, 512, 0, stream>>>(
      qpu_emb, 64,   w1bP + 1 * 65536, map_b1, ppP, 1,
      time_tab, 1000, w1bP + 3 * 65536, sch_b1, ptP);

  // keys + fused scores (pipelined 4 tiles/block)
  gemm_gather5<<<2048, 256, 0, stream>>>(
      pqP, ppP, map_qubit, map_qpu, wextP, map_b2,
      pgP, ptP, sched_gate, sched_time, wextP + 272 * 256, sch_b2,
      keysP, scoreP, pmaxP);

  // softmax stats over scores
  k_smax2<<<1, 256, 0, stream>>>(pmaxP, mhP);
  k_ssum<<<256, 256, 0, stream>>>(scoreP, mhP, spartP);
  k_ssum2<<<1, 256, 0, stream>>>(spartP, sinvP);

  // weighted key sum -> ctx -> attn_out
  k_u<<<512, 256, 0, stream>>>(keysP, scoreP, mhP, sinvP, uP);
  k_attn<<<1, 256, 0, stream>>>(uP, Wv, bv, Wo, bo, attnP, apadP);

  // logits + global softmax
  k_logits2<<<1024, 256, 0, stream>>>(keysP, apadP, logitsOut, bmaxP);
  k_lred1<<<1, 256, 0, stream>>>(bmaxP, mlP);
  k_lsum<<<512, 256, 0, stream>>>(logitsOut, mlP, lpartP);
  k_lred2<<<1, 256, 0, stream>>>(lpartP, slinvP);
  k_probs<<<1024, 256, 0, stream>>>(logitsOut, mlP, slinvP, probsOut);
}

// Round 4
// 717.061 us; speedup vs baseline: 2.5715x; 1.1725x over previous
//
#include <hip/hip_runtime.h>
#include <cstdint>
#include <cstddef>

typedef __bf16 bf16_t;
typedef __bf16 bf16x8 __attribute__((ext_vector_type(8)));
typedef __bf16 bf16x4 __attribute__((ext_vector_type(4)));
typedef float f32x4 __attribute__((ext_vector_type(4)));

#define A_TOTAL 262144
#define NMAP    131072

// ---------------- W1 slices f32 -> bf16 ------------------------------------
__global__ __launch_bounds__(256) void k_w1b16(
    const float* __restrict__ mW1, const float* __restrict__ sW1,
    bf16_t* __restrict__ dst) {
  int e = blockIdx.x * 256 + threadIdx.x;     // 0..262143
  int slice = e >> 16, idx = e & 65535;
  int n = idx >> 8, k = idx & 255;
  float v;
  switch (slice) {
    case 0:  v = mW1[n * 512 + k]; break;
    case 1:  v = mW1[n * 512 + 256 + k]; break;
    case 2:  v = sW1[n * 512 + k]; break;
    default: v = sW1[n * 512 + 256 + k]; break;
  }
  dst[e] = (bf16_t)v;
}

// ---------------- column partial sums of all_embeddings [131072][256] ------
__global__ __launch_bounds__(256) void k_mean(const float* __restrict__ A,
                                              float* __restrict__ part) {
  int t = threadIdx.x, b = blockIdx.x;        // 256 blocks x 512 rows
  const float* base = A + (size_t)b * 512 * 256 + t;
  float s = 0.f;
  for (int r = 0; r < 512; ++r) s += base[(size_t)r * 256];
  part[b * 256 + t] = s;
}

// ---------------- g -> query MLP -> q -> qk -> qw[2][4][256] f32 -----------
__global__ __launch_bounds__(256) void k_front(
    const float* __restrict__ meanPart,
    const float* __restrict__ qgW1, const float* __restrict__ qgb1,
    const float* __restrict__ qgW2, const float* __restrict__ qgb2,
    const float* __restrict__ Wq,  const float* __restrict__ bq,
    const float* __restrict__ Wk,
    const float* __restrict__ mW2, const float* __restrict__ sW2,
    float* __restrict__ qw) {
  __shared__ float g[256], h1[256], qry[256], qv[256];
  __shared__ float qks[4][256];
  int t = threadIdx.x;
  float s = 0.f;
  for (int b = 0; b < 256; ++b) s += meanPart[b * 256 + t];
  g[t] = s * (1.0f / 131072.0f);
  __syncthreads();
  {
    const f32x4* row = (const f32x4*)(qgW1 + (size_t)t * 256);
    float acc = 0.f;
    for (int k = 0; k < 64; ++k) {
      f32x4 w = row[k];
      acc += w[0] * g[4 * k] + w[1] * g[4 * k + 1] + w[2] * g[4 * k + 2] + w[3] * g[4 * k + 3];
    }
    h1[t] = fmaxf(acc + qgb1[t], 0.f);
  }
  __syncthreads();
  {
    const f32x4* row = (const f32x4*)(qgW2 + (size_t)t * 256);
    float acc = 0.f;
    for (int k = 0; k < 64; ++k) {
      f32x4 w = row[k];
      acc += w[0] * h1[4 * k] + w[1] * h1[4 * k + 1] + w[2] * h1[4 * k + 2] + w[3] * h1[4 * k + 3];
    }
    qry[t] = acc + qgb2[t];
  }
  __syncthreads();
  {
    const f32x4* row = (const f32x4*)(Wq + (size_t)t * 256);
    float acc = 0.f;
    for (int k = 0; k < 64; ++k) {
      f32x4 w = row[k];
      acc += w[0] * qry[4 * k] + w[1] * qry[4 * k + 1] + w[2] * qry[4 * k + 2] + w[3] * qry[4 * k + 3];
    }
    qv[t] = acc + bq[t];
  }
  __syncthreads();
  // qk[h][n] = (1/8) sum_d qv[h*64+d] * Wk[h*64+d][n]
  for (int h = 0; h < 4; ++h) {
    float acc = 0.f;
    for (int d = 0; d < 64; ++d) acc += qv[h * 64 + d] * Wk[(size_t)(h * 64 + d) * 256 + t];
    qks[h][t] = acc * 0.125f;
  }
  __syncthreads();
  // qw[tab][h][k] = sum_n qk[h][n] * W2tab[n][k]
  for (int tab = 0; tab < 2; ++tab) {
    const float* W2 = tab ? sW2 : mW2;
    float acc0 = 0.f, acc1 = 0.f, acc2 = 0.f, acc3 = 0.f;
    for (int n = 0; n < 256; ++n) {
      float wv = W2[(size_t)n * 256 + t];
      acc0 += qks[0][n] * wv;
      acc1 += qks[1][n] * wv;
      acc2 += qks[2][n] * wv;
      acc3 += qks[3][n] * wv;
    }
    float* dst = qw + tab * 1024;
    dst[0 * 256 + t] = acc0;
    dst[1 * 256 + t] = acc1;
    dst[2 * 256 + t] = acc2;
    dst[3 * 256 + t] = acc3;
  }
}

// ---------------- GEMM (direct, merged 2 problem halves) -------------------
__global__ __launch_bounds__(512, 4) void gemm_direct3(
    const float* __restrict__ A0, int M0, const bf16_t* __restrict__ W0,
    const float* __restrict__ b0, bf16_t* __restrict__ C0, int split,
    const float* __restrict__ A1, int M1, const bf16_t* __restrict__ W1,
    const float* __restrict__ b1, bf16_t* __restrict__ C1) {
  __shared__ __align__(16) bf16_t Xo[128][264];   // 67584 B
  int blk = blockIdx.x;
  const float* A; int M; const bf16_t* W; const float* bias; bf16_t* C; int bid;
  if (blk < split) { A = A0; M = M0; W = W0; bias = b0; C = C0; bid = blk; }
  else             { A = A1; M = M1; W = W1; bias = b1; C = C1; bid = blk - split; }
  int t = threadIdx.x;
  int w = t >> 6, lane = t & 63;
  int lm = lane & 15, q = lane >> 4;
  int mloc0 = (w & 1) * 64;
  int m0 = bid * 128 + mloc0;
  int c0 = (w >> 1) * 64;
  int rows[4];
#pragma unroll
  for (int i = 0; i < 4; ++i) {
    int m = m0 + i * 16 + lm;
    rows[i] = m < M ? m : M - 1;
  }
  f32x4 acc[4][4] = {};
#pragma unroll
  for (int kt = 0; kt < 8; ++kt) {
    int k0 = kt * 32 + q * 8;
    bf16x8 b[4];
#pragma unroll
    for (int j = 0; j < 4; ++j)
      b[j] = *(const bf16x8*)(W + (size_t)(c0 + j * 16 + lm) * 256 + k0);
#pragma unroll
    for (int i = 0; i < 4; ++i) {
      const float* src = A + (size_t)rows[i] * 256 + k0;
      f32x4 lo = *(const f32x4*)src;
      f32x4 hi = *(const f32x4*)(src + 4);
      bf16x8 a;
#pragma unroll
      for (int x = 0; x < 4; ++x) { a[x] = (bf16_t)lo[x]; a[x + 4] = (bf16_t)hi[x]; }
#pragma unroll
      for (int j = 0; j < 4; ++j)
        acc[i][j] = __builtin_amdgcn_mfma_f32_16x16x32_bf16(a, b[j], acc[i][j], 0, 0, 0);
    }
  }
#pragma unroll
  for (int j = 0; j < 4; ++j) {
    int col = c0 + j * 16 + lm;
    float bb = bias ? bias[col] : 0.f;
#pragma unroll
    for (int i = 0; i < 4; ++i)
#pragma unroll
      for (int r = 0; r < 4; ++r)
        Xo[mloc0 + i * 16 + q * 4 + r][col] = (bf16_t)(acc[i][j][r] + bb);
  }
  __syncthreads();
  size_t tile0 = (size_t)bid * 128;
  const char* lds = (const char*)&Xo[0][0];
#pragma unroll
  for (int s = 0; s < 8; ++s) {
    int flat = s * 8192 + t * 16;
    int row = flat >> 9, colb = flat & 511;
    if (tile0 + (size_t)row < (size_t)M) {
      uint4 v = *(const uint4*)(lds + row * 528 + colb);
      *(uint4*)((char*)C + tile0 * 512 + (size_t)flat) = v;
    }
  }
}

// ---------------- gather+relu -> X  + fused scores (no GEMM) ---------------
// X[a] = relu(Pa[ia]+Pb[ib]); scores[h,a] = X[a] . qw[half][h].
// 256 thr, 64 rows/block, 32 lanes per row (16B chunks). 4096 blocks.
__global__ __launch_bounds__(256) void k_gx(
    const bf16_t* __restrict__ Pa0, const bf16_t* __restrict__ Pb0,
    const int* __restrict__ idxA0, const int* __restrict__ idxB0,
    const bf16_t* __restrict__ Pa1, const bf16_t* __restrict__ Pb1,
    const int* __restrict__ idxA1, const int* __restrict__ idxB1,
    const float* __restrict__ qw,
    bf16_t* __restrict__ X, float* __restrict__ scores,
    float* __restrict__ partMax) {
  __shared__ float qs[4][256];
  __shared__ float sc[4][64];
  int t = threadIdx.x;
  int b = blockIdx.x;
  int rows0 = b * 64;
  int half = rows0 >= NMAP ? 1 : 0;
  const bf16_t* Pa = half ? Pa1 : Pa0;
  const bf16_t* Pb = half ? Pb1 : Pb0;
  const int* idxA = half ? idxA1 : idxA0;
  const int* idxB = half ? idxB1 : idxB0;
  int lrow0 = rows0 - half * NMAP;

  // stage qw for this half (4 KB)
  {
    f32x4 v = *(const f32x4*)(qw + half * 1024 + t * 4);
    *(f32x4*)&((float*)qs)[t * 4] = v;
  }

  int rg = t >> 5;          // row-in-group 0..7
  int cl = t & 31;          // 16B chunk lane
  // preload all indices (16 scalar loads in flight)
  int ia[8], ib[8];
#pragma unroll
  for (int it = 0; it < 8; ++it) {
    ia[it] = idxA[lrow0 + it * 8 + rg];
    ib[it] = idxB[lrow0 + it * 8 + rg];
  }
  __syncthreads();          // qs ready

#pragma unroll
  for (int it = 0; it < 8; ++it) {
    int rowg = it * 8 + rg;
    bf16x8 a8 = *(const bf16x8*)(Pa + (size_t)ia[it] * 256 + cl * 8);
    bf16x8 b8 = *(const bf16x8*)(Pb + (size_t)ib[it] * 256 + cl * 8);
    float x[8];
    bf16x8 xo;
#pragma unroll
    for (int e = 0; e < 8; ++e) {
      x[e] = fmaxf((float)a8[e] + (float)b8[e], 0.f);
      xo[e] = (bf16_t)x[e];
    }
    *(bf16x8*)(X + (size_t)(rows0 + rowg) * 256 + cl * 8) = xo;
    float p[4] = {0.f, 0.f, 0.f, 0.f};
#pragma unroll
    for (int h = 0; h < 4; ++h)
#pragma unroll
      for (int e = 0; e < 8; ++e)
        p[h] += x[e] * qs[h][cl * 8 + e];
#pragma unroll
    for (int h = 0; h < 4; ++h) {
#pragma unroll
      for (int o = 16; o > 0; o >>= 1) p[h] += __shfl_xor(p[h], o);
      if (cl == 0) sc[h][rowg] = p[h];
    }
  }
  __syncthreads();
  // scores write (coalesced per head) + per-block per-head max
  {
    int h = t >> 6, l = t & 63;
    float v = sc[h][l];
    scores[(size_t)h * A_TOTAL + rows0 + l] = v;
    float m = v;
#pragma unroll
    for (int o = 32; o > 0; o >>= 1) m = fmaxf(m, __shfl_xor(m, o));
    if (l == 0) partMax[h * 4096 + b] = m;
  }
}

// ---------------- per-head max over 4096 tile partials ---------------------
__global__ __launch_bounds__(256) void k_smax2(const float* __restrict__ pM,
                                               float* __restrict__ Mh) {
  int t = threadIdx.x;
  __shared__ float red[256];
  for (int h = 0; h < 4; ++h) {
    float m = -3.4e38f;
    for (int i = t; i < 4096; i += 256) m = fmaxf(m, pM[h * 4096 + i]);
    red[t] = m;
    __syncthreads();
    for (int s = 128; s > 0; s >>= 1) {
      if (t < s) red[t] = fmaxf(red[t], red[t + s]);
      __syncthreads();
    }
    if (t == 0) Mh[h] = red[0];
    __syncthreads();
  }
}

__global__ __launch_bounds__(256) void k_ssum(const float* __restrict__ scores,
                                              const float* __restrict__ Mh,
                                              float* __restrict__ part) {
  int b = blockIdx.x, t = threadIdx.x;    // 256 blocks, head = b>>6
  float m = Mh[b >> 6];
  const float* base = scores + (size_t)b * 4096;
  float s = 0.f;
  for (int i = 0; i < 16; ++i) s += __expf(base[i * 256 + t] - m);
  __shared__ float red[256];
  red[t] = s;
  __syncthreads();
  for (int st = 128; st > 0; st >>= 1) {
    if (t < st) red[t] += red[t + st];
    __syncthreads();
  }
  if (t == 0) part[b] = red[0];
}

__global__ __launch_bounds__(256) void k_ssum2(const float* __restrict__ part,
                                               float* __restrict__ invS) {
  int t = threadIdx.x;
  __shared__ float red[256];
  red[t] = part[t];
  __syncthreads();
  for (int s = 32; s > 0; s >>= 1) {
    if ((t & 63) < s) red[t] += red[t + s];
    __syncthreads();
  }
  if ((t & 63) == 0) invS[t >> 6] = 1.0f / red[t];
}

// ---------------- y[half][h] = sum_a w[h,a]*X[a]; shalf = sum_a w ----------
__global__ __launch_bounds__(256) void k_u3(
    const bf16_t* __restrict__ X, const float* __restrict__ scores,
    const float* __restrict__ Mh, const float* __restrict__ invS,
    float* __restrict__ y, float* __restrict__ shalf) {
  __shared__ float wl[4][512];
  __shared__ float uloc[8][4][256];     // 32 KiB
  int t = threadIdx.x;
  int a0 = blockIdx.x * 512;            // 512 blocks x 512 rows
  int half = blockIdx.x >> 8;           // blocks 0..255 map, 256..511 sched
#pragma unroll
  for (int i = 0; i < 8; ++i) {
    int e = i * 256 + t;                // 0..2047
    int h = e >> 9, rr = e & 511;
    wl[h][rr] = __expf(scores[(size_t)h * A_TOTAL + a0 + rr] - Mh[h]) * invS[h];
  }
  __syncthreads();
  // per-head normalized-weight sum for this block
  {
    int h = t >> 6, l = t & 63;
    float s = 0.f;
#pragma unroll
    for (int j = 0; j < 8; ++j) s += wl[h][l + j * 64];
#pragma unroll
    for (int o = 32; o > 0; o >>= 1) s += __shfl_xor(s, o);
    if (l == 0) atomicAdd(&shalf[half * 4 + h], s);
  }
  int tc = t & 31, rh = t >> 5;         // 32 col-threads x 8 cols; 8 row groups
  float acc[4][8] = {};
  for (int rr = 0; rr < 64; ++rr) {
    int al = rh * 64 + rr;
    bf16x8 kv = *(const bf16x8*)(X + (size_t)(a0 + al) * 256 + tc * 8);
    float f[8];
#pragma unroll
    for (int e = 0; e < 8; ++e) f[e] = (float)kv[e];
#pragma unroll
    for (int h = 0; h < 4; ++h) {
      float wv = wl[h][al];
#pragma unroll
      for (int e = 0; e < 8; ++e) acc[h][e] += wv * f[e];
    }
  }
#pragma unroll
  for (int h = 0; h < 4; ++h)
#pragma unroll
    for (int e = 0; e < 8; ++e) uloc[rh][h][tc * 8 + e] = acc[h][e];
  __syncthreads();
#pragma unroll
  for (int h = 0; h < 4; ++h) {
    float v = 0.f;
#pragma unroll
    for (int g = 0; g < 8; ++g) v += uloc[g][h][t];
    atomicAdd(&y[(half * 4 + h) * 256 + t], v);
  }
}

// ---------------- u -> ctx -> attn_out, + per-half logit consts ------------
__global__ __launch_bounds__(256) void k_attn2(
    const float* __restrict__ y,      // [2][4][256]
    const float* __restrict__ shalf,  // [2][4]
    const float* __restrict__ mW2, const float* __restrict__ sW2,
    const float* __restrict__ mb2, const float* __restrict__ sb2,
    const float* __restrict__ Wv, const float* __restrict__ bv,
    const float* __restrict__ Wo, const float* __restrict__ bo,
    float* __restrict__ attnv, float* __restrict__ c01) {
  __shared__ float ys[2][4][256];
  __shared__ float us[4][256];
  __shared__ float ctx[256];
  __shared__ float att[256];
  __shared__ float r0[4], r1[4];
  int t = threadIdx.x;
#pragma unroll
  for (int i = 0; i < 8; ++i) ((float*)ys)[i * 256 + t] = y[i * 256 + t];
  __syncthreads();
  // u[h][j] = sum_k y0[h][k] mW2[j][k] + y1[h][k] sW2[j][k] + s0 mb2 + s1 sb2
  {
    int j = t;
    float a0 = 0.f, a1 = 0.f, a2 = 0.f, a3 = 0.f;
    const f32x4* rm = (const f32x4*)(mW2 + (size_t)j * 256);
    const f32x4* rs = (const f32x4*)(sW2 + (size_t)j * 256);
    for (int k = 0; k < 64; ++k) {
      f32x4 wm = rm[k], wsv = rs[k];
#pragma unroll
      for (int e = 0; e < 4; ++e) {
        float w0 = wm[e], w1 = wsv[e];
        int kk = k * 4 + e;
        a0 += ys[0][0][kk] * w0 + ys[1][0][kk] * w1;
        a1 += ys[0][1][kk] * w0 + ys[1][1][kk] * w1;
        a2 += ys[0][2][kk] * w0 + ys[1][2][kk] * w1;
        a3 += ys[0][3][kk] * w0 + ys[1][3][kk] * w1;
      }
    }
    float bm = mb2[j], bs = sb2[j];
    us[0][j] = a0 + shalf[0] * bm + shalf[4] * bs;
    us[1][j] = a1 + shalf[1] * bm + shalf[5] * bs;
    us[2][j] = a2 + shalf[2] * bm + shalf[6] * bs;
    us[3][j] = a3 + shalf[3] * bm + shalf[7] * bs;
  }
  __syncthreads();
  {
    int h = t >> 6;
    const f32x4* row = (const f32x4*)(Wv + (size_t)t * 256);
    const f32x4* uh = (const f32x4*)us[h];
    float acc = 0.f;
    for (int k = 0; k < 64; ++k) {
      f32x4 w = row[k], x = uh[k];
      acc += w[0] * x[0] + w[1] * x[1] + w[2] * x[2] + w[3] * x[3];
    }
    ctx[t] = acc + bv[t];
  }
  __syncthreads();
  {
    const f32x4* row = (const f32x4*)(Wo + (size_t)t * 256);
    const f32x4* cx = (const f32x4*)ctx;
    float acc = 0.f;
    for (int k = 0; k < 64; ++k) {
      f32x4 w = row[k], x = cx[k];
      acc += w[0] * x[0] + w[1] * x[1] + w[2] * x[2] + w[3] * x[3];
    }
    float v = acc + bo[t];
    att[t] = v;
    attnv[t] = v;
  }
  __syncthreads();
  // c_half = b2_half . attn_out
  {
    float p0 = mb2[t] * att[t], p1 = sb2[t] * att[t];
#pragma unroll
    for (int o = 32; o > 0; o >>= 1) {
      p0 += __shfl_xor(p0, o);
      p1 += __shfl_xor(p1, o);
    }
    if ((t & 63) == 0) { r0[t >> 6] = p0; r1[t >> 6] = p1; }
    __syncthreads();
    if (t == 0) c01[0] = r0[0] + r0[1] + r0[2] + r0[3];
    if (t == 1) c01[1] = r1[0] + r1[1] + r1[2] + r1[3];
  }
}

// ---------------- z_half = W2_half^T attn_out, padded to 16 rows bf16 ------
__global__ __launch_bounds__(256) void k_zc(
    const float* __restrict__ mW2, const float* __restrict__ sW2,
    const float* __restrict__ attnv, bf16_t* __restrict__ zpad) {
  int tab = blockIdx.x, t = threadIdx.x;
  const float* W2 = tab ? sW2 : mW2;
  __shared__ float att[256];
  att[t] = attnv[t];
  __syncthreads();
  float acc = 0.f;
  for (int j = 0; j < 256; ++j) acc += W2[(size_t)j * 256 + t] * att[j];
  bf16_t* dst = zpad + (size_t)tab * 16 * 256;
  dst[t] = (bf16_t)acc;
#pragma unroll
  for (int i = 1; i < 16; ++i) dst[i * 256 + t] = (bf16_t)0.f;
}

// ---------------- logits[a] = X[a].z_half + c_half (MFMA) + block max ------
__global__ __launch_bounds__(256) void k_logits3(
    const bf16_t* __restrict__ X, const bf16_t* __restrict__ zpad,
    const float* __restrict__ c01,
    float* __restrict__ out_logits, float* __restrict__ blockMax) {
  int t = threadIdx.x;
  int w = t >> 6, lane = t & 63;
  int lm = lane & 15, q = lane >> 4;
  int half = blockIdx.x >> 9;
  float c = c01[half];
  int m0 = blockIdx.x * 256 + w * 64;
  const bf16_t* zp = zpad + (size_t)half * 16 * 256;
  bf16x8 b[8];
#pragma unroll
  for (int kt = 0; kt < 8; ++kt)
    b[kt] = *(const bf16x8*)(zp + lm * 256 + kt * 32 + q * 8);
  f32x4 acc[4] = {};
#pragma unroll
  for (int i = 0; i < 4; ++i) {
    const bf16_t* arow = X + (size_t)(m0 + i * 16 + lm) * 256 + q * 8;
#pragma unroll
    for (int kt = 0; kt < 8; ++kt) {
      bf16x8 a = *(const bf16x8*)(arow + kt * 32);
      acc[i] = __builtin_amdgcn_mfma_f32_16x16x32_bf16(a, b[kt], acc[i], 0, 0, 0);
    }
  }
  float lmax = -3.4e38f;
  if (lm == 0) {
#pragma unroll
    for (int i = 0; i < 4; ++i) {
      f32x4 v4;
#pragma unroll
      for (int rr = 0; rr < 4; ++rr) {
        float v = acc[i][rr] + c;
        v4[rr] = v;
        lmax = fmaxf(lmax, v);
      }
      *(f32x4*)(out_logits + m0 + i * 16 + q * 4) = v4;
    }
  }
  float m1 = fmaxf(lmax, __shfl_xor(lmax, 16));
  float m2 = fmaxf(m1, __shfl_xor(m1, 32));
  __shared__ float red[4];
  if (lane == 0) red[w] = m2;
  __syncthreads();
  if (t == 0)
    blockMax[blockIdx.x] = fmaxf(fmaxf(red[0], red[1]), fmaxf(red[2], red[3]));
}

__global__ __launch_bounds__(256) void k_lred1(const float* __restrict__ bm,
                                               float* __restrict__ Ml) {
  int t = threadIdx.x;
  float m = -3.4e38f;
  for (int i = t; i < 1024; i += 256) m = fmaxf(m, bm[i]);
  __shared__ float red[256];
  red[t] = m;
  __syncthreads();
  for (int s = 128; s > 0; s >>= 1) {
    if (t < s) red[t] = fmaxf(red[t], red[t + s]);
    __syncthreads();
  }
  if (t == 0) Ml[0] = red[0];
}

__global__ __launch_bounds__(256) void k_lsum(const float* __restrict__ logits,
                                              const float* __restrict__ Ml,
                                              float* __restrict__ part) {
  int t = threadIdx.x, b = blockIdx.x;   // 512 blocks x 512 elems
  float m = Ml[0];
  float s = __expf(logits[b * 512 + t] - m) + __expf(logits[b * 512 + 256 + t] - m);
  __shared__ float red[256];
  red[t] = s;
  __syncthreads();
  for (int st = 128; st > 0; st >>= 1) {
    if (t < st) red[t] += red[t + st];
    __syncthreads();
  }
  if (t == 0) part[b] = red[0];
}

__global__ __launch_bounds__(256) void k_lred2(const float* __restrict__ part,
                                               float* __restrict__ invSl) {
  int t = threadIdx.x;
  float s = part[t] + part[t + 256];
  __shared__ float red[256];
  red[t] = s;
  __syncthreads();
  for (int st = 128; st > 0; st >>= 1) {
    if (t < st) red[t] += red[t + st];
    __syncthreads();
  }
  if (t == 0) invSl[0] = 1.0f / red[0];
}

__global__ __launch_bounds__(256) void k_probs(const float* __restrict__ logits,
                                               const float* __restrict__ Ml,
                                               const float* __restrict__ invSl,
                                               float* __restrict__ probs) {
  int i = blockIdx.x * 256 + threadIdx.x;
  probs[i] = __expf(logits[i] - Ml[0]) * invSl[0];
}

// ===========================================================================
extern "C" void kernel_launch(void* const* d_in, const int* in_sizes, int n_in,
                              void* d_out, int out_size, void* d_ws, size_t ws_size,
                              hipStream_t stream) {
  const float* qubit_emb = (const float*)d_in[0];
  const float* qpu_emb   = (const float*)d_in[1];
  const float* gate_emb  = (const float*)d_in[2];
  const float* all_emb   = (const float*)d_in[3];
  const float* time_tab  = (const float*)d_in[4];
  const float* map_W1 = (const float*)d_in[5];
  const float* map_b1 = (const float*)d_in[6];
  const float* map_W2 = (const float*)d_in[7];
  const float* map_b2 = (const float*)d_in[8];
  const float* sch_W1 = (const float*)d_in[9];
  const float* sch_b1 = (const float*)d_in[10];
  const float* sch_W2 = (const float*)d_in[11];
  const float* sch_b2 = (const float*)d_in[12];
  const float* qg_W1 = (const float*)d_in[13];
  const float* qg_b1 = (const float*)d_in[14];
  const float* qg_W2 = (const float*)d_in[15];
  const float* qg_b2 = (const float*)d_in[16];
  const float* Wq = (const float*)d_in[17];
  const float* bq = (const float*)d_in[18];
  const float* Wk = (const float*)d_in[19];
  // d_in[20] = attn_bk: per-head constant, softmax-invariant -> unused
  const float* Wv = (const float*)d_in[21];
  const float* bv = (const float*)d_in[22];
  const float* Wo = (const float*)d_in[23];
  const float* bo = (const float*)d_in[24];
  const int* map_qubit  = (const int*)d_in[25];
  const int* map_qpu    = (const int*)d_in[26];
  const int* sched_gate = (const int*)d_in[27];
  const int* sched_time = (const int*)d_in[28];
  (void)in_sizes; (void)n_in; (void)out_size;

  char* ws = (char*)d_ws;
  size_t off = 0;
  auto alloc = [&](size_t b) { size_t r = off; off += (b + 255) & ~(size_t)255; return r; };
  size_t XB    = alloc((size_t)A_TOTAL * 256 * 2);   // bf16 relu activations X
  size_t PQ    = alloc((size_t)65536 * 256 * 2);     // bf16 qubit proj
  size_t PG    = alloc((size_t)65536 * 256 * 2);     // bf16 gate proj
  size_t PP    = alloc((size_t)128 * 256 * 2);       // bf16 qpu proj (+b1)
  size_t PT    = alloc((size_t)1024 * 256 * 2);      // bf16 time proj (+b1)
  size_t W1B   = alloc((size_t)4 * 65536 * 2);       // bf16 W1 slices
  size_t QW    = alloc((size_t)2 * 4 * 256 * 4);     // f32 qw
  size_t SCORE = alloc((size_t)4 * A_TOTAL * 4);     // f32 scores [4][A]
  size_t MPART = alloc((size_t)256 * 256 * 4);       // mean partials
  size_t ZPAD  = alloc((size_t)2 * 16 * 256 * 2);    // bf16 z padded
  size_t ATTNV = alloc(256 * 4);
  size_t Y     = alloc(2 * 4 * 256 * 4);             // 8192 B (zeroed)
  size_t SH    = alloc(2 * 4 * 4);                   // 256 B block (zeroed)
  size_t C01   = alloc(2 * 4);
  size_t PMAX  = alloc(4 * 4096 * 4);
  size_t MH    = alloc(4 * 4);
  size_t SINV  = alloc(4 * 4);
  size_t BMAX  = alloc(1024 * 4);
  size_t ML    = alloc(4);
  size_t SLINV = alloc(4);
  size_t LPART = alloc(512 * 4);
  size_t SPART = alloc(256 * 4);
  if (off > ws_size) return;  // insufficient scratch -> loud validation fail

  bf16_t* xP     = (bf16_t*)(ws + XB);
  bf16_t* pqP    = (bf16_t*)(ws + PQ);
  bf16_t* pgP    = (bf16_t*)(ws + PG);
  bf16_t* ppP    = (bf16_t*)(ws + PP);
  bf16_t* ptP    = (bf16_t*)(ws + PT);
  bf16_t* w1bP   = (bf16_t*)(ws + W1B);
  float*  qwP    = (float*)(ws + QW);
  float*  scoreP = (float*)(ws + SCORE);
  float*  mpartP = (float*)(ws + MPART);
  bf16_t* zpadP  = (bf16_t*)(ws + ZPAD);
  float*  attnvP = (float*)(ws + ATTNV);
  float*  yP     = (float*)(ws + Y);
  float*  shP    = (float*)(ws + SH);
  float*  c01P   = (float*)(ws + C01);
  float*  pmaxP  = (float*)(ws + PMAX);
  float*  mhP    = (float*)(ws + MH);
  float*  sinvP  = (float*)(ws + SINV);
  float*  bmaxP  = (float*)(ws + BMAX);
  float*  mlP    = (float*)(ws + ML);
  float*  slinvP = (float*)(ws + SLINV);
  float*  lpartP = (float*)(ws + LPART);
  float*  spartP = (float*)(ws + SPART);

  float* probsOut  = (float*)d_out;
  float* logitsOut = probsOut + A_TOTAL;

  // zero y + shalf (contiguous alloc blocks: 8192 + 256)
  hipMemsetAsync(yP, 0, 8448, stream);

  k_w1b16<<<1024, 256, 0, stream>>>(map_W1, sch_W1, w1bP);
  k_mean<<<256, 256, 0, stream>>>(all_emb, mpartP);
  k_front<<<1, 256, 0, stream>>>(mpartP, qg_W1, qg_b1, qg_W2, qg_b2,
                                 Wq, bq, Wk, map_W2, sch_W2, qwP);

  // table projections (layer-1 halves): qubit+gate merged, qpu+time merged
  gemm_direct3<<<1024, 512, 0, stream>>>(
      qubit_emb, 65536, w1bP + 0 * 65536, nullptr, pqP, 512,
      gate_emb,  65536, w1bP + 2 * 65536, nullptr, pgP);
  gemm_direct3<<<9, 512, 0, stream>>>(
      qpu_emb, 64,   w1bP + 1 * 65536, map_b1, ppP, 1,
      time_tab, 1000, w1bP + 3 * 65536, sch_b1, ptP);

  // X = relu(gather sum) + fused scores (no W2 GEMM)
  k_gx<<<4096, 256, 0, stream>>>(
      pqP, ppP, map_qubit, map_qpu,
      pgP, ptP, sched_gate, sched_time,
      qwP, xP, scoreP, pmaxP);

  // softmax stats over scores
  k_smax2<<<1, 256, 0, stream>>>(pmaxP, mhP);
  k_ssum<<<256, 256, 0, stream>>>(scoreP, mhP, spartP);
  k_ssum2<<<1, 256, 0, stream>>>(spartP, sinvP);

  // weighted X sum (per half) -> u -> ctx -> attn_out -> z, consts
  k_u3<<<512, 256, 0, stream>>>(xP, scoreP, mhP, sinvP, yP, shP);
  k_attn2<<<1, 256, 0, stream>>>(yP, shP, map_W2, sch_W2, map_b2, sch_b2,
                                 Wv, bv, Wo, bo, attnvP, c01P);
  k_zc<<<2, 256, 0, stream>>>(map_W2, sch_W2, attnvP, zpadP);

  // logits + global softmax
  k_logits3<<<1024, 256, 0, stream>>>(xP, zpadP, c01P, logitsOut, bmaxP);
  k_lred1<<<1, 256, 0, stream>>>(bmaxP, mlP);
  k_lsum<<<512, 256, 0, stream>>>(logitsOut, mlP, lpartP);
  k_lred2<<<1, 256, 0, stream>>>(lpartP, slinvP);
  k_probs<<<1024, 256, 0, stream>>>(logitsOut, mlP, slinvP, probsOut);
}